// Round 1
// baseline (166.708 us; speedup 1.0000x reference)
//
#include <hip/hip_runtime.h>

#define NTOK 1024
#define DDIM 128
#define NBC 64
#define BM 64
#define BN 64
#define NITER 16
#define EPS 1e-7f

typedef _Float16 f16;
typedef _Float16 f16x4 __attribute__((ext_vector_type(4)));
typedef _Float16 f16x8 __attribute__((ext_vector_type(8)));
typedef float f32x16 __attribute__((ext_vector_type(16)));

// LDS row strides (f16 elements). Chosen so row_base is 16B-aligned (b128 ok)
// and start-bank = 4*row%32 -> balanced 4 requests/bank for b128 frag reads.
#define SQS 136  // Xq/Xm: 128 + 8 pad
#define STS 72   // XmT:   64 + 8 pad
#define SPS 72   // P:     64 + 8 pad

// ---------------- prepass: norms + f16 copy + f16 transposed copy ----------
__global__ __launch_bounds__(256) void prep_kernel(
    const float* __restrict__ x, f16* __restrict__ xh,
    f16* __restrict__ xhT, float* __restrict__ norms) {
  int bx = blockIdx.x;
  int bc = bx & 63;
  int nt = bx >> 6;  // 0..7 (tiles of 128 rows)
  int n0 = nt * 128;
  __shared__ f16 sT[128 * 132];  // [n][d], pad 4
  int t = threadIdx.x;

  const float4* xv = (const float4*)(x + ((size_t)bc * NTOK + n0) * DDIM);
#pragma unroll
  for (int k = 0; k < 16; ++k) {
    int idx = t + 256 * k;
    int row = idx >> 5;  // 0..127 (half-wave per row)
    int c4 = idx & 31;   // float4 col, 32 cover full row of 128
    float4 v = xv[(size_t)row * 32 + c4];
    float ss = v.x * v.x + v.y * v.y + v.z * v.z + v.w * v.w;
    ss += __shfl_xor(ss, 1);
    ss += __shfl_xor(ss, 2);
    ss += __shfl_xor(ss, 4);
    ss += __shfl_xor(ss, 8);
    ss += __shfl_xor(ss, 16);
    if ((t & 31) == 0) norms[(size_t)bc * NTOK + n0 + row] = sqrtf(ss);
    f16x4 hv = {(f16)v.x, (f16)v.y, (f16)v.z, (f16)v.w};
    *(f16x4*)(xh + ((size_t)bc * NTOK + n0 + row) * DDIM + c4 * 4) = hv;
    *(f16x4*)(sT + row * 132 + c4 * 4) = hv;
  }
  __syncthreads();
  // transposed write: thread t -> d-row t>>1, n-half t&1 (64 n = 128B)
  int dr = t >> 1;
  int half = t & 1;
  f16* dst = xhT + ((size_t)bc * DDIM + dr) * NTOK + n0 + 64 * half;
#pragma unroll
  for (int s = 0; s < 8; ++s) {
    f16x8 tmp;
#pragma unroll
    for (int j = 0; j < 8; ++j) tmp[j] = sT[(64 * half + s * 8 + j) * 132 + dr];
    *(f16x8*)(dst + s * 8) = tmp;
  }
}

// ---------------- main: flash-style cos-attention --------------------------
__global__ __launch_bounds__(256) void cos_att_main(
    const f16* __restrict__ xh, const f16* __restrict__ xhT,
    const float* __restrict__ norms, const float* __restrict__ beta,
    float* __restrict__ out) {
  int bx = blockIdx.x;
  int bc = bx & 63;   // bc minor: concurrent blocks share q-tile -> beta L2 reuse
  int qt = bx >> 6;
  int q0 = qt * BM;

  __shared__ f16 sXq[64 * SQS];
  __shared__ f16 sXm[64 * SQS];
  __shared__ f16 sXmT[128 * STS];
  __shared__ f16 sP[64 * SPS];
  __shared__ float sNq[64];

  int t = threadIdx.x;
  int lane = t & 63;
  int w = t >> 6;
  int l31 = lane & 31;
  int hi = lane >> 5;  // 0/1: k-half within mfma frag

  // stage Xq (once)
  const f16* xq_g = xh + ((size_t)bc * NTOK + q0) * DDIM;
#pragma unroll
  for (int k = 0; k < 4; ++k) {
    int idx = t + 256 * k;
    int row = idx >> 4;
    int ch = idx & 15;
    *(f16x8*)(sXq + row * SQS + ch * 8) =
        *(const f16x8*)(xq_g + row * DDIM + ch * 8);
  }
  if (t < 64) sNq[t] = norms[(size_t)bc * NTOK + q0 + t];

  int i_str = (w >> 1) * 32;  // q-row strip (GEMM1 & GEMM2)
  int m_str = (w & 1) * 32;   // m strip (GEMM1)
  int d_str = (w & 1) * 64;   // d strip (GEMM2, 2 tiles)

  f32x16 o0, o1;
#pragma unroll
  for (int z = 0; z < 16; ++z) {
    o0[z] = 0.f;
    o1[z] = 0.f;
  }

  for (int mi = 0; mi < NITER; ++mi) {
    int m0 = mi * BN;
    __syncthreads();  // prev-iter GEMM2 done before overwriting LDS
    // stage Xm (row-major, d contiguous)
    const f16* xm_g = xh + ((size_t)bc * NTOK + m0) * DDIM;
#pragma unroll
    for (int k = 0; k < 4; ++k) {
      int idx = t + 256 * k;
      int row = idx >> 4;
      int ch = idx & 15;
      *(f16x8*)(sXm + row * SQS + ch * 8) =
          *(const f16x8*)(xm_g + row * DDIM + ch * 8);
    }
    // stage XmT (column copy, m contiguous) from pre-transposed global
    const f16* xt_g = xhT + (size_t)bc * DDIM * NTOK + m0;
#pragma unroll
    for (int k = 0; k < 4; ++k) {
      int idx = t + 256 * k;
      int drow = idx >> 3;
      int ch = idx & 7;
      *(f16x8*)(sXmT + drow * STS + ch * 8) =
          *(const f16x8*)(xt_g + (size_t)drow * NTOK + ch * 8);
    }
    // per-lane column norm + beta prefetch (in flight across GEMM1)
    float nm_l = norms[(size_t)bc * NTOK + m0 + m_str + l31];
    float bv[16];
#pragma unroll
    for (int r = 0; r < 16; ++r) {
      int rowl = (r & 3) + 8 * (r >> 2) + 4 * hi;
      bv[r] = beta[(size_t)(q0 + i_str + rowl) * NTOK + m0 + m_str + l31];
    }
    __syncthreads();

    // GEMM1: S[32x32] = Xq_strip . Xm_strip^T, K=128
    f32x16 s;
#pragma unroll
    for (int z = 0; z < 16; ++z) s[z] = 0.f;
#pragma unroll
    for (int kk = 0; kk < 8; ++kk) {
      f16x8 a = *(const f16x8*)(sXq + (i_str + l31) * SQS + kk * 16 + hi * 8);
      f16x8 b = *(const f16x8*)(sXm + (m_str + l31) * SQS + kk * 16 + hi * 8);
      s = __builtin_amdgcn_mfma_f32_32x32x16_f16(a, b, s, 0, 0, 0);
    }
    // P = sigmoid(beta * S / (nq*nm + eps)) -> f16 -> LDS [i][m]
#pragma unroll
    for (int r = 0; r < 16; ++r) {
      int rowl = (r & 3) + 8 * (r >> 2) + 4 * hi;
      float nq = sNq[i_str + rowl];
      float cosv = s[r] * __builtin_amdgcn_rcpf(nq * nm_l + EPS);
      float tt = bv[r] * cosv;
      float p = __builtin_amdgcn_rcpf(1.0f + __expf(-tt));
      sP[(i_str + rowl) * SPS + m_str + l31] = (f16)p;
    }
    __syncthreads();

    // GEMM2: O[32 x 64] += P_strip[32x64] . Xm[64 x d], K=64, 2 d-tiles
#pragma unroll
    for (int kk = 0; kk < 4; ++kk) {
      f16x8 pa = *(const f16x8*)(sP + (i_str + l31) * SPS + kk * 16 + hi * 8);
      f16x8 b0 =
          *(const f16x8*)(sXmT + (d_str + l31) * STS + kk * 16 + hi * 8);
      f16x8 b1 =
          *(const f16x8*)(sXmT + (d_str + 32 + l31) * STS + kk * 16 + hi * 8);
      o0 = __builtin_amdgcn_mfma_f32_32x32x16_f16(pa, b0, o0, 0, 0, 0);
      o1 = __builtin_amdgcn_mfma_f32_32x32x16_f16(pa, b1, o1, 0, 0, 0);
    }
  }

  // epilogue: fp32 coalesced (128B per half-wave per store)
  float* og = out + ((size_t)bc * NTOK + q0 + i_str) * DDIM;
#pragma unroll
  for (int r = 0; r < 16; ++r) {
    int rowl = (r & 3) + 8 * (r >> 2) + 4 * hi;
    og[(size_t)rowl * DDIM + d_str + l31] = o0[r];
    og[(size_t)rowl * DDIM + d_str + 32 + l31] = o1[r];
  }
}

extern "C" void kernel_launch(void* const* d_in, const int* in_sizes, int n_in,
                              void* d_out, int out_size, void* d_ws,
                              size_t ws_size, hipStream_t stream) {
  const float* x = (const float*)d_in[0];
  const float* beta = (const float*)d_in[1];
  float* out = (float*)d_out;

  char* ws = (char*)d_ws;
  float* norms = (float*)ws;                         // 64*1024*4   = 256 KB
  f16* xh = (f16*)(ws + (256 << 10));                // 8.4M * 2    = 16 MB
  f16* xhT = (f16*)(ws + (256 << 10) + (16 << 20));  // 16 MB

  prep_kernel<<<512, 256, 0, stream>>>(x, xh, xhT, norms);
  cos_att_main<<<1024, 256, 0, stream>>>(xh, xhT, norms, beta, out);
}

// Round 3
// 152.317 us; speedup vs baseline: 1.0945x; 1.0945x over previous
//
#include <hip/hip_runtime.h>

#define NTOK 1024
#define DDIM 128
#define EPS 1e-7f

typedef _Float16 f16;
typedef _Float16 f16x4 __attribute__((ext_vector_type(4)));
typedef _Float16 f16x8 __attribute__((ext_vector_type(8)));
typedef float f32x16 __attribute__((ext_vector_type(16)));
typedef unsigned int uint;

#define AS1 __attribute__((address_space(1)))
#define AS3 __attribute__((address_space(3)))

// ---------------- prepass: normalized f16 copy + unscaled f16 transpose ----
__global__ __launch_bounds__(256) void prep_kernel(
    const float* __restrict__ x, f16* __restrict__ xhn, f16* __restrict__ xhT) {
  int bx = blockIdx.x;
  int bc = bx & 63;
  int nt = bx >> 6;  // 0..7, tiles of 128 rows
  int n0 = nt * 128;
  __shared__ f16 sT[128 * 132];
  int t = threadIdx.x;

  const float4* xv = (const float4*)(x + ((size_t)bc * NTOK + n0) * DDIM);
#pragma unroll
  for (int k = 0; k < 16; ++k) {
    int idx = t + 256 * k;
    int row = idx >> 5;  // 0..127, 32 threads per row
    int c4 = idx & 31;
    float4 v = xv[(size_t)row * 32 + c4];
    float ss = v.x * v.x + v.y * v.y + v.z * v.z + v.w * v.w;
    ss += __shfl_xor(ss, 1);
    ss += __shfl_xor(ss, 2);
    ss += __shfl_xor(ss, 4);
    ss += __shfl_xor(ss, 8);
    ss += __shfl_xor(ss, 16);
    float rn = (ss > 0.f) ? rsqrtf(ss) : 0.f;
    f16x4 hn = {(f16)(v.x * rn), (f16)(v.y * rn), (f16)(v.z * rn),
                (f16)(v.w * rn)};
    *(f16x4*)(xhn + ((size_t)bc * NTOK + n0 + row) * DDIM + c4 * 4) = hn;
    f16x4 hv = {(f16)v.x, (f16)v.y, (f16)v.z, (f16)v.w};
    *(f16x4*)(sT + row * 132 + c4 * 4) = hv;
  }
  __syncthreads();
  int dr = t >> 1;
  int half = t & 1;
  f16* dst = xhT + ((size_t)bc * DDIM + dr) * NTOK + n0 + 64 * half;
#pragma unroll
  for (int s = 0; s < 8; ++s) {
    f16x8 tmp;
#pragma unroll
    for (int j = 0; j < 8; ++j) tmp[j] = sT[(64 * half + s * 8 + j) * 132 + dr];
    *(f16x8*)(dst + s * 8) = tmp;
  }
}

// ---------------- betaT[m][i] = beta[i][m] --------------------------------
__global__ __launch_bounds__(256) void transpose_beta(
    const float* __restrict__ b, float* __restrict__ bt) {
  __shared__ float s[64][65];
  int bi = blockIdx.x & 15;  // i tile
  int bj = blockIdx.x >> 4;  // m tile
  int t = threadIdx.x;
  int r = t >> 4;
  int c4 = (t & 15) * 4;
#pragma unroll
  for (int rr = 0; rr < 64; rr += 16) {
    float4 v =
        *(const float4*)(b + (size_t)(bi * 64 + r + rr) * NTOK + bj * 64 + c4);
    s[r + rr][c4] = v.x;
    s[r + rr][c4 + 1] = v.y;
    s[r + rr][c4 + 2] = v.z;
    s[r + rr][c4 + 3] = v.w;
  }
  __syncthreads();
#pragma unroll
  for (int rr = 0; rr < 64; rr += 16) {
    int m = r + rr;
    float4 v = {s[c4][m], s[c4 + 1][m], s[c4 + 2][m], s[c4 + 3][m]};
    *(float4*)(bt + (size_t)(bj * 64 + m) * NTOK + bi * 64 + c4) = v;
  }
}

// ---------------- main ------------------------------------------------------
// Per block: q-tile of 64 rows; 16 m-tiles of 64. S^T in regs, P via shfl
// transpose, O^T accumulated in regs, pair-reduced + transposed via LDS.
__global__ __launch_bounds__(256, 2) void cos_att_main(
    const f16* __restrict__ xhn, const f16* __restrict__ xhT,
    const float* __restrict__ betaT, float* __restrict__ out) {
  __shared__ __align__(16) char smem[65536];  // dbuf: [b*32K]=sXm(16K)+sXmT(16K)
  int bx = blockIdx.x;
  int bc = bx & 63;  // bc minor: concurrent blocks share q-tile -> betaT reuse
  int qt = bx >> 6;
  int q0 = qt * 64;

  int t = threadIdx.x;
  int lane = t & 63;
  int w = t >> 6;
  int l31 = lane & 31;
  int hi = lane >> 5;
  int i_str = (w >> 1) * 32;
  int m_str = (w & 1) * 32;

  // Xq B-frags in registers (constant across all 16 iters)
  f16x8 xq[8];
  {
    const f16* base =
        xhn + ((size_t)bc * NTOK + q0 + i_str + l31) * DDIM + hi * 8;
#pragma unroll
    for (int kk = 0; kk < 8; ++kk) xq[kk] = *(const f16x8*)(base + kk * 16);
  }

  // async stage of m-tile `mi` into buffer b (XOR-swizzled, conflict-free)
  auto stage = [&](int mi, int b) {
    int m0 = mi * 64;
    char* ldsm = smem + b * 32768;
    char* ldst = ldsm + 16384;
    {  // sXm: 64 rows x 256B. LDS[r][c'] = G[r][(c'&8)|((c'&7)^(r&7))]
      int lr = lane >> 4;
      int cp = lane & 15;
      const f16* gb = xhn + ((size_t)bc * NTOK + m0) * DDIM;
#pragma unroll
      for (int j = 0; j < 4; ++j) {
        int r = 16 * w + 4 * j + lr;
        int g = (cp & 8) | ((cp & 7) ^ (r & 7));
        const f16* gp = gb + (size_t)r * DDIM + g * 8;
        __builtin_amdgcn_global_load_lds(
            (const AS1 uint*)gp, (AS3 uint*)(ldsm + (16 * w + 4 * j) * 256),
            16, 0, 0);
      }
    }
    {  // sXmT: 128 rows x 128B. LDS[d][c'] = G[d][c'^(d&7)]
      int lr = lane >> 3;
      int cp = lane & 7;
      const f16* gb = xhT + (size_t)bc * DDIM * NTOK + m0;
#pragma unroll
      for (int j = 0; j < 4; ++j) {
        int d = 32 * w + 8 * j + lr;
        int g = cp ^ (d & 7);
        const f16* gp = gb + (size_t)d * NTOK + g * 8;
        __builtin_amdgcn_global_load_lds(
            (const AS1 uint*)gp, (AS3 uint*)(ldst + (32 * w + 8 * j) * 128),
            16, 0, 0);
      }
    }
  };

  stage(0, 0);

  f32x16 o[4];
#pragma unroll
  for (int dt = 0; dt < 4; ++dt)
#pragma unroll
    for (int z = 0; z < 16; ++z) o[dt][z] = 0.f;

  for (int mi = 0; mi < 16; ++mi) {
    int b = mi & 1;
    int m0 = mi * 64;
    __syncthreads();  // buf[b] DMA drained; prev reads of buf[1-b] done
    if (mi < 15) stage(mi + 1, 1 - b);

    // betaT prefetch (coalesced 128B rows)
    float bv[16];
    const float* bb = betaT + (size_t)(m0 + m_str) * NTOK + q0 + i_str + l31;
#pragma unroll
    for (int r = 0; r < 16; ++r) {
      int rowl = (r & 3) + 8 * (r >> 2) + 4 * hi;
      bv[r] = bb[(size_t)rowl * NTOK];
    }

    const char* ldsm = smem + b * 32768;
    const char* ldst = ldsm + 16384;

    // GEMM1: S^T[m][i] = Xm . Xq^T  (A = Xm rows, B = xq regs), K=128
    f32x16 s;
#pragma unroll
    for (int z = 0; z < 16; ++z) s[z] = 0.f;
    {
      int rA = m_str + l31;
      const char* rowA = ldsm + rA * 256;
      int rx = rA & 7;
#pragma unroll
      for (int kk = 0; kk < 8; ++kk) {
        int g = 2 * kk + hi;
        int cp = (g & 8) | ((g & 7) ^ rx);
        f16x8 a = *(const f16x8*)(rowA + cp * 16);
        s = __builtin_amdgcn_mfma_f32_32x32x16_f16(a, xq[kk], s, 0, 0, 0);
      }
    }

    // P = sigmoid(beta * cos), pack pairs to f16x2 dwords
    float pk[8];
#pragma unroll
    for (int rp = 0; rp < 8; ++rp) {
      float t0 = bv[2 * rp] * s[2 * rp];
      float t1 = bv[2 * rp + 1] * s[2 * rp + 1];
      float e0 = __builtin_amdgcn_exp2f(-1.44269504f * t0);
      float e1 = __builtin_amdgcn_exp2f(-1.44269504f * t1);
      float p0 = __builtin_amdgcn_rcpf(1.0f + e0);
      float p1 = __builtin_amdgcn_rcpf(1.0f + e1);
      pk[rp] = __builtin_bit_cast(float, __builtin_amdgcn_cvt_pkrtz(p0, p1));
    }
    // lane^32 exchange -> B-operand fragments for GEMM2
    float qk[8];
#pragma unroll
    for (int rp = 0; rp < 8; ++rp) qk[rp] = __shfl_xor(pk[rp], 32);
    union {
      float f[4];
      f16x8 h;
    } bt0, bt1;
    bt0.f[0] = hi ? qk[2] : pk[0];
    bt0.f[1] = hi ? qk[3] : pk[1];
    bt0.f[2] = hi ? pk[2] : qk[0];
    bt0.f[3] = hi ? pk[3] : qk[1];
    bt1.f[0] = hi ? qk[6] : pk[4];
    bt1.f[1] = hi ? qk[7] : pk[5];
    bt1.f[2] = hi ? pk[6] : qk[4];
    bt1.f[3] = hi ? pk[7] : qk[5];

    // GEMM2: O^T[d][i] += XmT . P  (A = XmT rows d, B = P frags), K=32
#pragma unroll
    for (int dt = 0; dt < 4; ++dt) {
      int d = dt * 32 + l31;
      const char* rowT = ldst + d * 128;
      int dx = d & 7;
      int g0 = (m_str >> 3) + hi;
      f16x8 a0 = *(const f16x8*)(rowT + (g0 ^ dx) * 16);
      f16x8 a1 = *(const f16x8*)(rowT + ((g0 + 2) ^ dx) * 16);
      o[dt] = __builtin_amdgcn_mfma_f32_32x32x16_f16(a0, bt0.h, o[dt], 0, 0, 0);
      o[dt] = __builtin_amdgcn_mfma_f32_32x32x16_f16(a1, bt1.h, o[dt], 0, 0, 0);
    }
  }

  // epilogue: pair-reduce (m_str 0 + 32) and transpose via LDS, then store
  __syncthreads();
  float* sO = (float*)smem;  // [64][132]
  if ((w & 1) == 0) {
#pragma unroll
    for (int dt = 0; dt < 4; ++dt)
#pragma unroll
      for (int r = 0; r < 16; ++r) {
        int rowl = (r & 3) + 8 * (r >> 2) + 4 * hi;
        sO[(i_str + l31) * 132 + dt * 32 + rowl] = o[dt][r];
      }
  }
  __syncthreads();
  if (w & 1) {
#pragma unroll
    for (int dt = 0; dt < 4; ++dt)
#pragma unroll
      for (int r = 0; r < 16; ++r) {
        int rowl = (r & 3) + 8 * (r >> 2) + 4 * hi;
        sO[(i_str + l31) * 132 + dt * 32 + rowl] += o[dt][r];
      }
  }
  __syncthreads();
  float* og = out + ((size_t)bc * NTOK + q0) * DDIM;
#pragma unroll
  for (int k = 0; k < 8; ++k) {
    int idx = t + 256 * k;
    int row = idx >> 5;
    int c4 = idx & 31;
    *(float4*)(og + (size_t)row * DDIM + c4 * 4) =
        *(const float4*)(sO + row * 132 + c4 * 4);
  }
}

extern "C" void kernel_launch(void* const* d_in, const int* in_sizes, int n_in,
                              void* d_out, int out_size, void* d_ws,
                              size_t ws_size, hipStream_t stream) {
  const float* x = (const float*)d_in[0];
  const float* beta = (const float*)d_in[1];
  float* out = (float*)d_out;

  char* ws = (char*)d_ws;
  f16* xhn = (f16*)ws;                       // 16 MB
  f16* xhT = (f16*)(ws + (16 << 20));        // 16 MB
  float* betaT = (float*)(ws + (32 << 20));  // 4 MB

  prep_kernel<<<512, 256, 0, stream>>>(x, xhn, xhT);
  transpose_beta<<<256, 256, 0, stream>>>(beta, betaT);
  cos_att_main<<<1024, 256, 0, stream>>>(xhn, xhT, betaT, out);
}